// Round 14
// baseline (306.571 us; speedup 1.0000x reference)
//
#include <hip/hip_runtime.h>
#include <cstdint>

typedef __bf16 bf16_t;
typedef __bf16 bf16x4 __attribute__((ext_vector_type(4)));
typedef __bf16 bf16x8 __attribute__((ext_vector_type(8)));
typedef float f32x4 __attribute__((ext_vector_type(4)));
typedef unsigned int u32x2 __attribute__((ext_vector_type(2)));
typedef unsigned int u32x4 __attribute__((ext_vector_type(4)));

#define B_ 4
#define C_ 256
#define N_ 4096
#define NH_ 4
#define HD_ 64

static __device__ __forceinline__ f32x4 mfma_bf16(bf16x8 a, bf16x8 b, f32x4 c) {
  return __builtin_amdgcn_mfma_f32_16x16x32_bf16(a, b, c, 0, 0, 0);
}

static __device__ __forceinline__ void async16(const void* g, void* l) {
  __builtin_amdgcn_global_load_lds(
      (__attribute__((address_space(1))) void*)(uintptr_t)g,
      (__attribute__((address_space(3))) void*)(uint32_t)(uintptr_t)l,
      16, 0, 0);
}

static __device__ __forceinline__ float fexp2(float x) {
#if __has_builtin(__builtin_amdgcn_exp2f)
  return __builtin_amdgcn_exp2f(x);  // raw v_exp_f32
#else
  return exp2f(x);
#endif
}

static __device__ __forceinline__ unsigned pack_bf16(float lo, float hi) {
  bf16x4 t;
  t[0] = (bf16_t)lo;
  t[1] = (bf16_t)hi;
  return *(unsigned*)&t;
}

// ---------------- kernel 1: GN stats -> per-(b,c) affine ----------------
__global__ __launch_bounds__(256) void k_gn_stats(const float* __restrict__ x,
                                                  const float* __restrict__ gn_w,
                                                  const float* __restrict__ gn_b,
                                                  float* __restrict__ gnscale,
                                                  float* __restrict__ gnshift) {
  const int bg = blockIdx.x;
  const int b = bg >> 5, g = bg & 31;
  const float4* p4 = (const float4*)(x + (size_t)(b * C_ + g * 8) * N_);
  float s = 0.f, ss = 0.f;
  for (int i = threadIdx.x; i < 8192; i += 256) {
    float4 v = p4[i];
    s += (v.x + v.y) + (v.z + v.w);
    ss += (v.x * v.x + v.y * v.y) + (v.z * v.z + v.w * v.w);
  }
  for (int off = 32; off > 0; off >>= 1) {
    s += __shfl_down(s, off);
    ss += __shfl_down(ss, off);
  }
  __shared__ float red_s[4], red_ss[4];
  const int wid = threadIdx.x >> 6, lane = threadIdx.x & 63;
  if (lane == 0) { red_s[wid] = s; red_ss[wid] = ss; }
  __syncthreads();
  if (threadIdx.x < 8) {
    float S = (red_s[0] + red_s[1]) + (red_s[2] + red_s[3]);
    float SS = (red_ss[0] + red_ss[1]) + (red_ss[2] + red_ss[3]);
    float mean = S * (1.f / 32768.f);
    float var = SS * (1.f / 32768.f) - mean * mean;
    float rstd = rsqrtf(var + 1e-5f);
    int c = g * 8 + threadIdx.x;
    float w = gn_w[c];
    gnscale[b * C_ + c] = w * rstd;
    gnshift[b * C_ + c] = gn_b[c] - mean * rstd * w;
  }
}

// ---------------- kernel 2: weight fp32 -> bf16 ----------------
__global__ __launch_bounds__(256) void k_conv_w(const float* __restrict__ qkv_w,
                                                const float* __restrict__ out_w,
                                                bf16_t* __restrict__ w1,
                                                bf16_t* __restrict__ w2) {
  int i = blockIdx.x * 256 + threadIdx.x;
  if (i < 3 * C_ * C_) w1[i] = (bf16_t)qkv_w[i];
  else w2[i - 3 * C_ * C_] = (bf16_t)out_w[i - 3 * C_ * C_];
}

// ---------------- kernel 3: GN apply + transpose (LDS-coalesced) ----------------
__global__ __launch_bounds__(256) void k_gn_apply(const float* __restrict__ x,
                                                  const float* __restrict__ gnscale,
                                                  const float* __restrict__ gnshift,
                                                  bf16_t* __restrict__ h) {
  __shared__ bf16_t T[32 * 258];
  const int t = threadIdx.x;
  const int tok0 = blockIdx.x * 32;
  const int b = tok0 >> 12;
  const int n0 = tok0 & (N_ - 1);
  const int nl = t & 31, cset = t >> 5;
  const float* xb = x + ((size_t)(b * C_ + cset * 32) << 12) + n0 + nl;
  const float* scp = gnscale + b * C_ + cset * 32;
  const float* shp = gnshift + b * C_ + cset * 32;
#pragma unroll
  for (int j = 0; j < 32; ++j) {
    float y = xb[(size_t)j << 12] * scp[j] + shp[j];
    T[nl * 258 + cset * 32 + j] = (bf16_t)y;
  }
  __syncthreads();
  const int c4 = t & 63;
#pragma unroll
  for (int p = 0; p < 8; ++p) {
    const int tokl = p * 4 + (t >> 6);
    const int idx = tokl * 258 + c4 * 4;
    uint2 v;
    v.x = *(const unsigned*)&T[idx];
    v.y = *(const unsigned*)&T[idx + 2];
    *(uint2*)(h + ((size_t)(tok0 + tokl) << 8) + c4 * 4) = v;
  }
}

// ---------------- kernel 4: QKV GEMM ----------------
__global__ __launch_bounds__(256) void k_gemm_qkv(const bf16_t* __restrict__ h,
                                                  const bf16_t* __restrict__ w1,
                                                  const float* __restrict__ qkv_b,
                                                  bf16_t* __restrict__ Qb,
                                                  bf16_t* __restrict__ Kb,
                                                  bf16_t* __restrict__ Vb) {
  __shared__ bf16_t As[128 * 32], Bs[128 * 32];
  const int tid = threadIdx.x, lane = tid & 63, wid = tid >> 6;
  const int g = lane >> 4, q = lane & 15;
  const int wm = wid >> 1, wn = wid & 1;
  const int m0 = blockIdx.x * 128;
  const int o0 = blockIdx.y * 128;
  f32x4 acc[4][4] = {};
  const int srow = lane >> 2, scol = (lane & 3) * 8;
  for (int kc = 0; kc < 8; ++kc) {
    const int k0 = kc * 32;
#pragma unroll
    for (int j = 0; j < 2; ++j) {
      const int chunk = wid + j * 4;
      async16(h + (size_t)(m0 + chunk * 16 + srow) * C_ + k0 + scol, &As[chunk * 512]);
      async16(w1 + (size_t)(o0 + chunk * 16 + srow) * C_ + k0 + scol, &Bs[chunk * 512]);
    }
    __syncthreads();
    bf16x8 a[4], bb[4];
#pragma unroll
    for (int t = 0; t < 4; ++t) {
      a[t] = *(const bf16x8*)&As[(wm * 64 + t * 16 + q) * 32 + g * 8];
      bb[t] = *(const bf16x8*)&Bs[(wn * 64 + t * 16 + q) * 32 + g * 8];
    }
#pragma unroll
    for (int mi = 0; mi < 4; ++mi)
#pragma unroll
      for (int ni = 0; ni < 4; ++ni)
        acc[mi][ni] = mfma_bf16(a[mi], bb[ni], acc[mi][ni]);
    __syncthreads();
  }
  const float QSCALE = 0.1803368801111244f;  // (1/sqrt(64)) * log2(e)
#pragma unroll
  for (int ni = 0; ni < 4; ++ni) {
    const int o = o0 + wn * 64 + ni * 16 + q;
    const float bias = qkv_b[o];
    const int mat = o >> 8;
    const int c = o & 255, hh = c >> 6, d = c & 63;
#pragma unroll
    for (int mi = 0; mi < 4; ++mi) {
      const int tokb = m0 + wm * 64 + mi * 16 + g * 4;
      const int b = tokb >> 12, n = tokb & (N_ - 1);
      const size_t bh = (size_t)(b * NH_ + hh);
      f32x4 t = acc[mi][ni] + bias;
      if (mat == 0) {
#pragma unroll
        for (int r = 0; r < 4; ++r)
          Qb[(bh * N_ + n + r) * HD_ + d] = (bf16_t)(t[r] * QSCALE);
      } else if (mat == 1) {
#pragma unroll
        for (int r = 0; r < 4; ++r)
          Kb[(bh * N_ + n + r) * HD_ + d] = (bf16_t)t[r];
      } else {
        *(bf16x4*)(Vb + (bh * HD_ + d) * N_ + n) = __builtin_convertvector(t, bf16x4);
      }
    }
  }
}

// ---------------- kernel 5: flash attention — NO-LDS, barrier-free ----------------
// 4 waves/block (256 thr), 32 q/wave, split-4. K/V fragments read directly
// from global: per XCD the working K+V is ~2 MB (L2-resident via the
// XCD-contiguous swizzle); a block's waves re-read the same 16 KB tile stream
// (L1 catches re-reads). No __syncthreads -> waves free-run, MFMA/VALU phases
// of different waves overlap naturally.
__global__ __launch_bounds__(256) void k_attn(const bf16_t* __restrict__ Qb,
                                              const bf16_t* __restrict__ Kb,
                                              const bf16_t* __restrict__ Vb,
                                              bf16_t* __restrict__ op0,
                                              bf16_t* __restrict__ op1,
                                              bf16_t* __restrict__ op23,
                                              float* __restrict__ lsum) {
  const int tid = threadIdx.x, lane = tid & 63, wid = tid >> 6;  // wid 0..3
  const int g = lane >> 4, q = lane & 15;
  int bid = blockIdx.x;
  bid = (bid & 7) * 256 + (bid >> 3);  // XCD-contiguous (2048 % 8 == 0)
  const int kh = bid & 3;
  const int qt = (bid >> 2) & 31;   // 32 q-groups of 128 q
  const int bh = bid >> 7;          // 16 heads; 2 per XCD
  const int nq0 = qt * 128 + wid * 32;
  const int k00 = kh * (N_ / 4);
  const int NT = (N_ / 4) / 64;  // 16
  const size_t base = (size_t)bh << 18;
  const bf16_t* Qp = Qb + base;
  const bf16_t* Kp = Kb + base;
  const bf16_t* Vp = Vb + base;

  const bf16x8 bqA0 = *(const bf16x8*)(Qp + (size_t)(nq0 + q) * HD_ + g * 8);
  const bf16x8 bqA1 = *(const bf16x8*)(Qp + (size_t)(nq0 + q) * HD_ + 32 + g * 8);
  const bf16x8 bqB0 = *(const bf16x8*)(Qp + (size_t)(nq0 + 16 + q) * HD_ + g * 8);
  const bf16x8 bqB1 = *(const bf16x8*)(Qp + (size_t)(nq0 + 16 + q) * HD_ + 32 + g * 8);

  f32x4 laccA = {}, laccB = {};
  f32x4 accA[4] = {}, accB[4] = {};
  bf16x8 ones;
#pragma unroll
  for (int i = 0; i < 8; ++i) ones[i] = (bf16_t)1.0f;

  // per-lane K/V base pointers (row q, columns g*8 / 32+g*8)
  const bf16_t* kRow = Kp + (size_t)(k00 + q) * HD_;
  const bf16_t* vRow = Vp + (size_t)q * N_ + k00;

  for (int t = 0; t < NT; ++t) {
    const int nk0 = t * 64;
    f32x4 z = {0.f, 0.f, 0.f, 0.f};
    f32x4 sA[4], sB[4];
    // ---- QK^T: K fragments direct from global ----
#pragma unroll
    for (int kb = 0; kb < 4; ++kb) {
      const bf16_t* kr = kRow + (size_t)(nk0 + kb * 16) * HD_;
      bf16x8 k0 = *(const bf16x8*)(kr + g * 8);
      bf16x8 k1 = *(const bf16x8*)(kr + 32 + g * 8);
      __builtin_amdgcn_s_setprio(1);
      sA[kb] = mfma_bf16(k0, bqA0, z);
      sB[kb] = mfma_bf16(k0, bqB0, z);
      sA[kb] = mfma_bf16(k1, bqA1, sA[kb]);
      sB[kb] = mfma_bf16(k1, bqB1, sB[kb]);
      __builtin_amdgcn_s_setprio(0);
    }
    // ---- P = exp2(s), no max subtraction ----
#pragma unroll
    for (int kb = 0; kb < 4; ++kb)
#pragma unroll
      for (int r = 0; r < 4; ++r) {
        sA[kb][r] = fexp2(sA[kb][r]);
        sB[kb][r] = fexp2(sB[kb][r]);
      }
    // ---- register transpose P^T -> B-operand frags ----
    bf16x8 pbA[2], pbB[2];
#pragma unroll
    for (int s = 0; s < 2; ++s) {
      const f32x4* st = s ? sB : sA;
      bf16x8* pb = s ? pbB : pbA;
#pragma unroll
      for (int h = 0; h < 2; ++h) {
        unsigned u0 = pack_bf16(st[2 * h][0], st[2 * h][1]);
        unsigned u1 = pack_bf16(st[2 * h][2], st[2 * h][3]);
        unsigned u2 = pack_bf16(st[2 * h + 1][0], st[2 * h + 1][1]);
        unsigned u3 = pack_bf16(st[2 * h + 1][2], st[2 * h + 1][3]);
        u32x4 w;
#if __has_builtin(__builtin_amdgcn_permlane32_swap) && __has_builtin(__builtin_amdgcn_permlane16_swap)
        u32x2 a02 = __builtin_amdgcn_permlane32_swap(u0, u2, false, false);
        u32x2 r02 = __builtin_amdgcn_permlane16_swap(a02[0], a02[1], false, false);
        u32x2 a13 = __builtin_amdgcn_permlane32_swap(u1, u3, false, false);
        u32x2 r13 = __builtin_amdgcn_permlane16_swap(a13[0], a13[1], false, false);
        w[0] = r02[0]; w[2] = r02[1]; w[1] = r13[0]; w[3] = r13[1];
#else
        const int sl0 = (g & 1) * 32 + q, sl1 = sl0 + 16;
        w[0] = (g < 2) ? __shfl((int)u0, sl0) : __shfl((int)u2, sl0);
        w[1] = (g < 2) ? __shfl((int)u1, sl0) : __shfl((int)u3, sl0);
        w[2] = (g < 2) ? __shfl((int)u0, sl1) : __shfl((int)u2, sl1);
        w[3] = (g < 2) ? __shfl((int)u1, sl1) : __shfl((int)u3, sl1);
#endif
        pb[h] = *(bf16x8*)&w;
      }
    }
    // ---- l-sum via ones-row MFMA + PV (V fragments direct from global) ----
    __builtin_amdgcn_s_setprio(1);
    laccA = mfma_bf16(ones, pbA[0], laccA);
    laccA = mfma_bf16(ones, pbA[1], laccA);
    laccB = mfma_bf16(ones, pbB[0], laccB);
    laccB = mfma_bf16(ones, pbB[1], laccB);
    __builtin_amdgcn_s_setprio(0);
#pragma unroll
    for (int db = 0; db < 4; ++db) {
      const bf16_t* vr = vRow + (size_t)(db * 16) * N_ + nk0;
      bf16x8 v0 = *(const bf16x8*)(vr + g * 8);
      bf16x8 v1 = *(const bf16x8*)(vr + 32 + g * 8);
      __builtin_amdgcn_s_setprio(1);
      accA[db] = mfma_bf16(v0, pbA[0], accA[db]);
      accB[db] = mfma_bf16(v0, pbB[0], accB[db]);
      accA[db] = mfma_bf16(v1, pbA[1], accA[db]);
      accB[db] = mfma_bf16(v1, pbB[1], accB[db]);
      __builtin_amdgcn_s_setprio(0);
    }
  }

  bf16_t* Op;
  if (kh == 0) Op = op0 + (size_t)bh * N_ * HD_;
  else if (kh == 1) Op = op1 + (size_t)bh * N_ * HD_;
  else Op = op23 + (size_t)((kh - 2) * 16 + bh) * N_ * HD_;
  bf16_t* opA = Op + (size_t)(nq0 + q) * HD_;
  bf16_t* opB = opA + 16 * HD_;
#pragma unroll
  for (int db = 0; db < 4; ++db) {
    *(bf16x4*)(opA + db * 16 + g * 4) = __builtin_convertvector(accA[db], bf16x4);
    *(bf16x4*)(opB + db * 16 + g * 4) = __builtin_convertvector(accB[db], bf16x4);
  }
  if (g == 0) {
    const size_t mlb = (size_t)(kh * 16 + bh) * N_;
    lsum[mlb + nq0 + q] = laccA[0];
    lsum[mlb + nq0 + 16 + q] = laccB[0];
  }
}

// ---------------- kernel 5b: combine the four key-quarters ----------------
__global__ __launch_bounds__(256) void k_attn_combine(const bf16_t* __restrict__ op0,
                                                      const bf16_t* __restrict__ op1,
                                                      const bf16_t* __restrict__ op23,
                                                      const float* __restrict__ lsum,
                                                      bf16_t* __restrict__ att) {
  const int gid = blockIdx.x * 256 + threadIdx.x;  // 524288
  const int d8 = gid & 7;
  const int q = (gid >> 3) & (N_ - 1);
  const int bh = gid >> 15;
  const size_t ro = ((size_t)bh * N_ + q) * HD_ + d8 * 8;
  const float l = lsum[(size_t)bh * N_ + q] + lsum[(size_t)(16 + bh) * N_ + q] +
                  lsum[(size_t)(32 + bh) * N_ + q] + lsum[(size_t)(48 + bh) * N_ + q];
  const float inv = 1.0f / l;
  const bf16x8 o0 = *(const bf16x8*)(op0 + ro);
  const bf16x8 o1 = *(const bf16x8*)(op1 + ro);
  const bf16x8 o2 = *(const bf16x8*)(op23 + ro);
  const bf16x8 o3 = *(const bf16x8*)(op23 + (size_t)16 * N_ * HD_ + ro);
  bf16x8 r;
#pragma unroll
  for (int j = 0; j < 8; ++j)
    r[j] = (bf16_t)((((float)o0[j] + (float)o1[j]) + ((float)o2[j] + (float)o3[j])) * inv);
  const int b = bh >> 2, hh = bh & 3;
  *(bf16x8*)(att + ((size_t)b * N_ + q) * C_ + hh * HD_ + d8 * 8) = r;
}

// ---------------- kernel 6: out-proj GEMM + bias + residual ----------------
__global__ __launch_bounds__(256) void k_gemm_out(const bf16_t* __restrict__ att,
                                                  const bf16_t* __restrict__ w2,
                                                  const float* __restrict__ out_b,
                                                  const float* __restrict__ x,
                                                  float* __restrict__ out) {
  __shared__ bf16_t As[128 * 32], Bs[128 * 32];
  const int tid = threadIdx.x, lane = tid & 63, wid = tid >> 6;
  const int g = lane >> 4, q = lane & 15;
  const int wm = wid >> 1, wn = wid & 1;
  const int m0 = blockIdx.x * 128;
  const int o0 = blockIdx.y * 128;
  f32x4 acc[4][4] = {};
  const int srow = lane >> 2, scol = (lane & 3) * 8;
  for (int kc = 0; kc < 8; ++kc) {
    const int k0 = kc * 32;
#pragma unroll
    for (int j = 0; j < 2; ++j) {
      const int chunk = wid + j * 4;
      async16(att + (size_t)(m0 + chunk * 16 + srow) * C_ + k0 + scol, &As[chunk * 512]);
      async16(w2 + (size_t)(o0 + chunk * 16 + srow) * C_ + k0 + scol, &Bs[chunk * 512]);
    }
    __syncthreads();
    bf16x8 a[4], bb[4];
#pragma unroll
    for (int t = 0; t < 4; ++t) {
      a[t] = *(const bf16x8*)&As[(wm * 64 + t * 16 + q) * 32 + g * 8];
      bb[t] = *(const bf16x8*)&Bs[(wn * 64 + t * 16 + q) * 32 + g * 8];
    }
#pragma unroll
    for (int mi = 0; mi < 4; ++mi)
#pragma unroll
      for (int ni = 0; ni < 4; ++ni)
        acc[mi][ni] = mfma_bf16(a[mi], bb[ni], acc[mi][ni]);
    __syncthreads();
  }
#pragma unroll
  for (int ni = 0; ni < 4; ++ni) {
    const int o = o0 + wn * 64 + ni * 16 + q;
    const float bias = out_b[o];
#pragma unroll
    for (int mi = 0; mi < 4; ++mi) {
      const int tokb = m0 + wm * 64 + mi * 16 + g * 4;
      const int b = tokb >> 12, n = tokb & (N_ - 1);
      const size_t idx = ((size_t)(b * C_ + o) << 12) + n;
      const float4 xv = *(const float4*)(x + idx);
      f32x4 t = acc[mi][ni];
      float4 r = make_float4(t[0] + bias + xv.x, t[1] + bias + xv.y,
                             t[2] + bias + xv.z, t[3] + bias + xv.w);
      *(float4*)(out + idx) = r;
    }
  }
}

extern "C" void kernel_launch(void* const* d_in, const int* in_sizes, int n_in,
                              void* d_out, int out_size, void* d_ws, size_t ws_size,
                              hipStream_t stream) {
  (void)in_sizes; (void)n_in; (void)out_size; (void)ws_size;
  const float* x = (const float*)d_in[0];
  const float* gn_w = (const float*)d_in[1];
  const float* gn_b = (const float*)d_in[2];
  const float* qkv_w = (const float*)d_in[3];
  const float* qkv_b = (const float*)d_in[4];
  const float* out_w = (const float*)d_in[5];
  const float* out_b = (const float*)d_in[6];
  float* out = (float*)d_out;

  char* ws = (char*)d_ws;
  float* gnscale = (float*)ws;              // 1024 f32
  float* gnshift = gnscale + 1024;          // 1024 f32
  bf16_t* w1bf = (bf16_t*)(ws + 8192);      // 196608 bf16
  bf16_t* w2bf = w1bf + 196608;             // 65536 bf16
  bf16_t* hbuf = w2bf + 65536;              // 4194304 bf16; Opart kh0 during attn
  bf16_t* Qb = hbuf + 4194304;              // Q; att buffer after combine
  bf16_t* Kb = Qb + 4194304;
  bf16_t* Vb = Kb + 4194304;
  bf16_t* op1 = Vb + 4194304;               // 4194304 bf16 (Opart kh1)
  float* lsum = (float*)(op1 + 4194304);    // 262144 f32
  bf16_t* op23 = (bf16_t*)d_out;            // Opart kh2,3 (rewritten by gemm_out)

  k_gn_stats<<<128, 256, 0, stream>>>(x, gn_w, gn_b, gnscale, gnshift);
  k_conv_w<<<1024, 256, 0, stream>>>(qkv_w, out_w, w1bf, w2bf);
  k_gn_apply<<<512, 256, 0, stream>>>(x, gnscale, gnshift, hbuf);
  k_gemm_qkv<<<dim3(128, 6), 256, 0, stream>>>(hbuf, w1bf, qkv_b, Qb, Kb, Vb);
  k_attn<<<2048, 256, 0, stream>>>(Qb, Kb, Vb, hbuf, op1, op23, lsum);
  k_attn_combine<<<2048, 256, 0, stream>>>(hbuf, op1, op23, lsum, Qb);
  k_gemm_out<<<dim3(128, 2), 256, 0, stream>>>(Qb, w2bf, out_b, x, out);
}

// Round 15
// 121.729 us; speedup vs baseline: 2.5185x; 2.5185x over previous
//
#include <hip/hip_runtime.h>
#include <cstdint>

typedef __bf16 bf16_t;
typedef __bf16 bf16x4 __attribute__((ext_vector_type(4)));
typedef __bf16 bf16x8 __attribute__((ext_vector_type(8)));
typedef float f32x4 __attribute__((ext_vector_type(4)));
typedef unsigned int u32x2 __attribute__((ext_vector_type(2)));
typedef unsigned int u32x4 __attribute__((ext_vector_type(4)));

#define B_ 4
#define C_ 256
#define N_ 4096
#define NH_ 4
#define HD_ 64

static __device__ __forceinline__ f32x4 mfma_bf16(bf16x8 a, bf16x8 b, f32x4 c) {
  return __builtin_amdgcn_mfma_f32_16x16x32_bf16(a, b, c, 0, 0, 0);
}

static __device__ __forceinline__ void async16(const void* g, void* l) {
  __builtin_amdgcn_global_load_lds(
      (__attribute__((address_space(1))) void*)(uintptr_t)g,
      (__attribute__((address_space(3))) void*)(uint32_t)(uintptr_t)l,
      16, 0, 0);
}

static __device__ __forceinline__ float fexp2(float x) {
#if __has_builtin(__builtin_amdgcn_exp2f)
  return __builtin_amdgcn_exp2f(x);  // raw v_exp_f32
#else
  return exp2f(x);
#endif
}

static __device__ __forceinline__ unsigned pack_bf16(float lo, float hi) {
  bf16x4 t;
  t[0] = (bf16_t)lo;
  t[1] = (bf16_t)hi;
  return *(unsigned*)&t;
}

// ---------------- kernel 1: GN stats (blocks 0-127) + weight cast (blocks 128+) ----------------
__global__ __launch_bounds__(256) void k_pre(const float* __restrict__ x,
                                             const float* __restrict__ gn_w,
                                             const float* __restrict__ gn_b,
                                             const float* __restrict__ qkv_w,
                                             const float* __restrict__ out_w,
                                             float* __restrict__ gnscale,
                                             float* __restrict__ gnshift,
                                             bf16_t* __restrict__ w1,
                                             bf16_t* __restrict__ w2) {
  __shared__ float red_s[4], red_ss[4];
  if (blockIdx.x >= 128) {
    // weight fp32 -> bf16
    int i = (blockIdx.x - 128) * 256 + threadIdx.x;  // 0..262143
    if (i < 3 * C_ * C_) w1[i] = (bf16_t)qkv_w[i];
    else w2[i - 3 * C_ * C_] = (bf16_t)out_w[i - 3 * C_ * C_];
    return;
  }
  const int bg = blockIdx.x;
  const int b = bg >> 5, g = bg & 31;
  const float4* p4 = (const float4*)(x + (size_t)(b * C_ + g * 8) * N_);
  float s = 0.f, ss = 0.f;
  for (int i = threadIdx.x; i < 8192; i += 256) {
    float4 v = p4[i];
    s += (v.x + v.y) + (v.z + v.w);
    ss += (v.x * v.x + v.y * v.y) + (v.z * v.z + v.w * v.w);
  }
  for (int off = 32; off > 0; off >>= 1) {
    s += __shfl_down(s, off);
    ss += __shfl_down(ss, off);
  }
  const int wid = threadIdx.x >> 6, lane = threadIdx.x & 63;
  if (lane == 0) { red_s[wid] = s; red_ss[wid] = ss; }
  __syncthreads();
  if (threadIdx.x < 8) {
    float S = (red_s[0] + red_s[1]) + (red_s[2] + red_s[3]);
    float SS = (red_ss[0] + red_ss[1]) + (red_ss[2] + red_ss[3]);
    float mean = S * (1.f / 32768.f);
    float var = SS * (1.f / 32768.f) - mean * mean;
    float rstd = rsqrtf(var + 1e-5f);
    int c = g * 8 + threadIdx.x;
    float w = gn_w[c];
    gnscale[b * C_ + c] = w * rstd;
    gnshift[b * C_ + c] = gn_b[c] - mean * rstd * w;
  }
}

// ---------------- kernel 3: GN apply + transpose (LDS-coalesced) ----------------
__global__ __launch_bounds__(256) void k_gn_apply(const float* __restrict__ x,
                                                  const float* __restrict__ gnscale,
                                                  const float* __restrict__ gnshift,
                                                  bf16_t* __restrict__ h) {
  __shared__ bf16_t T[32 * 258];
  const int t = threadIdx.x;
  const int tok0 = blockIdx.x * 32;
  const int b = tok0 >> 12;
  const int n0 = tok0 & (N_ - 1);
  const int nl = t & 31, cset = t >> 5;
  const float* xb = x + ((size_t)(b * C_ + cset * 32) << 12) + n0 + nl;
  const float* scp = gnscale + b * C_ + cset * 32;
  const float* shp = gnshift + b * C_ + cset * 32;
#pragma unroll
  for (int j = 0; j < 32; ++j) {
    float y = xb[(size_t)j << 12] * scp[j] + shp[j];
    T[nl * 258 + cset * 32 + j] = (bf16_t)y;
  }
  __syncthreads();
  const int c4 = t & 63;
#pragma unroll
  for (int p = 0; p < 8; ++p) {
    const int tokl = p * 4 + (t >> 6);
    const int idx = tokl * 258 + c4 * 4;
    uint2 v;
    v.x = *(const unsigned*)&T[idx];
    v.y = *(const unsigned*)&T[idx + 2];
    *(uint2*)(h + ((size_t)(tok0 + tokl) << 8) + c4 * 4) = v;
  }
}

// ---------------- kernel 4: QKV GEMM ----------------
__global__ __launch_bounds__(256) void k_gemm_qkv(const bf16_t* __restrict__ h,
                                                  const bf16_t* __restrict__ w1,
                                                  const float* __restrict__ qkv_b,
                                                  bf16_t* __restrict__ Qb,
                                                  bf16_t* __restrict__ Kb,
                                                  bf16_t* __restrict__ Vb) {
  __shared__ bf16_t As[128 * 32], Bs[128 * 32];
  const int tid = threadIdx.x, lane = tid & 63, wid = tid >> 6;
  const int g = lane >> 4, q = lane & 15;
  const int wm = wid >> 1, wn = wid & 1;
  const int m0 = blockIdx.x * 128;
  const int o0 = blockIdx.y * 128;
  f32x4 acc[4][4] = {};
  const int srow = lane >> 2, scol = (lane & 3) * 8;
  for (int kc = 0; kc < 8; ++kc) {
    const int k0 = kc * 32;
#pragma unroll
    for (int j = 0; j < 2; ++j) {
      const int chunk = wid + j * 4;
      async16(h + (size_t)(m0 + chunk * 16 + srow) * C_ + k0 + scol, &As[chunk * 512]);
      async16(w1 + (size_t)(o0 + chunk * 16 + srow) * C_ + k0 + scol, &Bs[chunk * 512]);
    }
    __syncthreads();
    bf16x8 a[4], bb[4];
#pragma unroll
    for (int t = 0; t < 4; ++t) {
      a[t] = *(const bf16x8*)&As[(wm * 64 + t * 16 + q) * 32 + g * 8];
      bb[t] = *(const bf16x8*)&Bs[(wn * 64 + t * 16 + q) * 32 + g * 8];
    }
#pragma unroll
    for (int mi = 0; mi < 4; ++mi)
#pragma unroll
      for (int ni = 0; ni < 4; ++ni)
        acc[mi][ni] = mfma_bf16(a[mi], bb[ni], acc[mi][ni]);
    __syncthreads();
  }
  const float QSCALE = 0.1803368801111244f;  // (1/sqrt(64)) * log2(e)
#pragma unroll
  for (int ni = 0; ni < 4; ++ni) {
    const int o = o0 + wn * 64 + ni * 16 + q;
    const float bias = qkv_b[o];
    const int mat = o >> 8;
    const int c = o & 255, hh = c >> 6, d = c & 63;
#pragma unroll
    for (int mi = 0; mi < 4; ++mi) {
      const int tokb = m0 + wm * 64 + mi * 16 + g * 4;
      const int b = tokb >> 12, n = tokb & (N_ - 1);
      const size_t bh = (size_t)(b * NH_ + hh);
      f32x4 t = acc[mi][ni] + bias;
      if (mat == 0) {
#pragma unroll
        for (int r = 0; r < 4; ++r)
          Qb[(bh * N_ + n + r) * HD_ + d] = (bf16_t)(t[r] * QSCALE);
      } else if (mat == 1) {
#pragma unroll
        for (int r = 0; r < 4; ++r)
          Kb[(bh * N_ + n + r) * HD_ + d] = (bf16_t)t[r];
      } else {
        *(bf16x4*)(Vb + (bh * HD_ + d) * N_ + n) = __builtin_convertvector(t, bf16x4);
      }
    }
  }
}

// ---------------- kernel 5: flash attention — R5 structure, split-2, NO setprio ----------------
// 8 waves/block, 32 q/wave; 64-key double-buffered K/V (32 KB); no-max softmax;
// lsum via ones-row MFMA; P^T via permlane register transpose. 512 blocks.
// setprio removed: R9 measured +5% from dropping the scheduler region fences.
__global__ __launch_bounds__(512) void k_attn(const bf16_t* __restrict__ Qb,
                                              const bf16_t* __restrict__ Kb,
                                              const bf16_t* __restrict__ Vb,
                                              bf16_t* __restrict__ op0,
                                              bf16_t* __restrict__ op1,
                                              float* __restrict__ lsum) {
  __shared__ __align__(16) bf16_t Ks[2][4096];  // [buf][key(64)][d(64)]
  __shared__ __align__(16) bf16_t Vs[2][4096];  // [buf][d(64)][key(64)]
  const int tid = threadIdx.x, lane = tid & 63, wid = tid >> 6;  // wid 0..7
  const int g = lane >> 4, q = lane & 15;
  const int qs = q & 7;
  int bid = blockIdx.x;
  bid = (bid & 7) * 64 + (bid >> 3);  // XCD-contiguous (512 % 8 == 0)
  const int kh = bid & 1;
  const int qt = (bid >> 1) & 15;
  const int bh = bid >> 5;
  const int nq0 = qt * 256 + wid * 32;
  const int k00 = kh * (N_ / 2);
  const int NT = (N_ / 2) / 64;  // 32
  const size_t base = (size_t)bh << 18;
  const bf16_t* Qp = Qb + base;
  const bf16_t* Kp = Kb + base;
  const bf16_t* Vp = Vb + base;

  const bf16x8 bqA0 = *(const bf16x8*)(Qp + (size_t)(nq0 + q) * HD_ + g * 8);
  const bf16x8 bqA1 = *(const bf16x8*)(Qp + (size_t)(nq0 + q) * HD_ + 32 + g * 8);
  const bf16x8 bqB0 = *(const bf16x8*)(Qp + (size_t)(nq0 + 16 + q) * HD_ + g * 8);
  const bf16x8 bqB1 = *(const bf16x8*)(Qp + (size_t)(nq0 + 16 + q) * HD_ + 32 + g * 8);

  const int srow = lane >> 3;
  const int sc16 = (lane & 7) ^ srow;

  f32x4 laccA = {}, laccB = {};
  f32x4 accA[4] = {}, accB[4] = {};
  bf16x8 ones;
#pragma unroll
  for (int i = 0; i < 8; ++i) ones[i] = (bf16_t)1.0f;

  // prologue: 8 waves each stage one 1KB K-chunk and one 1KB V-chunk
  async16(Kp + (size_t)(k00 + wid * 8 + srow) * HD_ + sc16 * 8, &Ks[0][wid * 512]);
  async16(Vp + (size_t)(wid * 8 + srow) * N_ + k00 + sc16 * 8, &Vs[0][wid * 512]);
  __syncthreads();

  const bf16_t* kS = Kp + (size_t)(k00 + 64 + wid * 8 + srow) * HD_ + sc16 * 8;
  const bf16_t* vS = Vp + (size_t)(wid * 8 + srow) * N_ + k00 + 64 + sc16 * 8;

  for (int t = 0; t < NT; ++t) {
    const int buf = t & 1;
    if (t < NT - 1) {
      async16(kS, &Ks[buf ^ 1][wid * 512]);
      async16(vS, &Vs[buf ^ 1][wid * 512]);
      kS += 64 * HD_;
      vS += 64;
    }
    const bf16_t* Kl = Ks[buf];
    const bf16_t* Vl = Vs[buf];
    f32x4 z = {0.f, 0.f, 0.f, 0.f};
    f32x4 sA[4], sB[4];
#pragma unroll
    for (int kb = 0; kb < 4; ++kb) {
      bf16x8 k0 = *(const bf16x8*)(Kl + (kb * 16 + q) * 64 + ((g ^ qs) * 8));
      bf16x8 k1 = *(const bf16x8*)(Kl + (kb * 16 + q) * 64 + (((4 + g) ^ qs) * 8));
      sA[kb] = mfma_bf16(k0, bqA0, z);
      sB[kb] = mfma_bf16(k0, bqB0, z);
      sA[kb] = mfma_bf16(k1, bqA1, sA[kb]);
      sB[kb] = mfma_bf16(k1, bqB1, sB[kb]);
    }
    // ---- P = exp2(s), no max subtraction ----
#pragma unroll
    for (int kb = 0; kb < 4; ++kb)
#pragma unroll
      for (int r = 0; r < 4; ++r) {
        sA[kb][r] = fexp2(sA[kb][r]);
        sB[kb][r] = fexp2(sB[kb][r]);
      }
    // ---- register transpose P^T -> B-operand frags ----
    bf16x8 pbA[2], pbB[2];
#pragma unroll
    for (int s = 0; s < 2; ++s) {
      const f32x4* st = s ? sB : sA;
      bf16x8* pb = s ? pbB : pbA;
#pragma unroll
      for (int h = 0; h < 2; ++h) {
        unsigned u0 = pack_bf16(st[2 * h][0], st[2 * h][1]);
        unsigned u1 = pack_bf16(st[2 * h][2], st[2 * h][3]);
        unsigned u2 = pack_bf16(st[2 * h + 1][0], st[2 * h + 1][1]);
        unsigned u3 = pack_bf16(st[2 * h + 1][2], st[2 * h + 1][3]);
        u32x4 w;
#if __has_builtin(__builtin_amdgcn_permlane32_swap) && __has_builtin(__builtin_amdgcn_permlane16_swap)
        u32x2 a02 = __builtin_amdgcn_permlane32_swap(u0, u2, false, false);
        u32x2 r02 = __builtin_amdgcn_permlane16_swap(a02[0], a02[1], false, false);
        u32x2 a13 = __builtin_amdgcn_permlane32_swap(u1, u3, false, false);
        u32x2 r13 = __builtin_amdgcn_permlane16_swap(a13[0], a13[1], false, false);
        w[0] = r02[0]; w[2] = r02[1]; w[1] = r13[0]; w[3] = r13[1];
#else
        const int sl0 = (g & 1) * 32 + q, sl1 = sl0 + 16;
        w[0] = (g < 2) ? __shfl((int)u0, sl0) : __shfl((int)u2, sl0);
        w[1] = (g < 2) ? __shfl((int)u1, sl0) : __shfl((int)u3, sl0);
        w[2] = (g < 2) ? __shfl((int)u0, sl1) : __shfl((int)u2, sl1);
        w[3] = (g < 2) ? __shfl((int)u1, sl1) : __shfl((int)u3, sl1);
#endif
        pb[h] = *(bf16x8*)&w;
      }
    }
    // ---- l-sum via ones-row MFMA + PV ----
    laccA = mfma_bf16(ones, pbA[0], laccA);
    laccA = mfma_bf16(ones, pbA[1], laccA);
    laccB = mfma_bf16(ones, pbB[0], laccB);
    laccB = mfma_bf16(ones, pbB[1], laccB);
#pragma unroll
    for (int db = 0; db < 4; ++db) {
      bf16x8 v0 = *(const bf16x8*)(Vl + (db * 16 + q) * 64 + ((g ^ qs) * 8));
      bf16x8 v1 = *(const bf16x8*)(Vl + (db * 16 + q) * 64 + (((4 + g) ^ qs) * 8));
      accA[db] = mfma_bf16(v0, pbA[0], accA[db]);
      accB[db] = mfma_bf16(v0, pbB[0], accB[db]);
      accA[db] = mfma_bf16(v1, pbA[1], accA[db]);
      accB[db] = mfma_bf16(v1, pbB[1], accB[db]);
    }
    __syncthreads();
  }

  bf16_t* Op = (kh == 0 ? op0 : op1) + (size_t)bh * N_ * HD_;
  bf16_t* opA = Op + (size_t)(nq0 + q) * HD_;
  bf16_t* opB = opA + 16 * HD_;
#pragma unroll
  for (int db = 0; db < 4; ++db) {
    *(bf16x4*)(opA + db * 16 + g * 4) = __builtin_convertvector(accA[db], bf16x4);
    *(bf16x4*)(opB + db * 16 + g * 4) = __builtin_convertvector(accB[db], bf16x4);
  }
  if (g == 0) {
    const size_t mlb = (size_t)(kh * 16 + bh) * N_;
    lsum[mlb + nq0 + q] = laccA[0];
    lsum[mlb + nq0 + 16 + q] = laccB[0];
  }
}

// ---------------- kernel 5b: combine the two key-halves ----------------
__global__ __launch_bounds__(256) void k_attn_combine(const bf16_t* __restrict__ op0,
                                                      const bf16_t* __restrict__ op1,
                                                      const float* __restrict__ lsum,
                                                      bf16_t* __restrict__ att) {
  const int gid = blockIdx.x * 256 + threadIdx.x;  // 524288
  const int d8 = gid & 7;
  const int q = (gid >> 3) & (N_ - 1);
  const int bh = gid >> 15;
  const size_t ro = ((size_t)bh * N_ + q) * HD_ + d8 * 8;
  const float l = lsum[(size_t)bh * N_ + q] + lsum[(size_t)(16 + bh) * N_ + q];
  const float inv = 1.0f / l;
  const bf16x8 o0 = *(const bf16x8*)(op0 + ro);
  const bf16x8 o1 = *(const bf16x8*)(op1 + ro);
  bf16x8 r;
#pragma unroll
  for (int j = 0; j < 8; ++j)
    r[j] = (bf16_t)(((float)o0[j] + (float)o1[j]) * inv);
  const int b = bh >> 2, hh = bh & 3;
  *(bf16x8*)(att + ((size_t)b * N_ + q) * C_ + hh * HD_ + d8 * 8) = r;
}

// ---------------- kernel 6: out-proj GEMM + bias + residual ----------------
__global__ __launch_bounds__(256) void k_gemm_out(const bf16_t* __restrict__ att,
                                                  const bf16_t* __restrict__ w2,
                                                  const float* __restrict__ out_b,
                                                  const float* __restrict__ x,
                                                  float* __restrict__ out) {
  __shared__ bf16_t As[128 * 32], Bs[128 * 32];
  const int tid = threadIdx.x, lane = tid & 63, wid = tid >> 6;
  const int g = lane >> 4, q = lane & 15;
  const int wm = wid >> 1, wn = wid & 1;
  const int m0 = blockIdx.x * 128;
  const int o0 = blockIdx.y * 128;
  f32x4 acc[4][4] = {};
  const int srow = lane >> 2, scol = (lane & 3) * 8;
  for (int kc = 0; kc < 8; ++kc) {
    const int k0 = kc * 32;
#pragma unroll
    for (int j = 0; j < 2; ++j) {
      const int chunk = wid + j * 4;
      async16(att + (size_t)(m0 + chunk * 16 + srow) * C_ + k0 + scol, &As[chunk * 512]);
      async16(w2 + (size_t)(o0 + chunk * 16 + srow) * C_ + k0 + scol, &Bs[chunk * 512]);
    }
    __syncthreads();
    bf16x8 a[4], bb[4];
#pragma unroll
    for (int t = 0; t < 4; ++t) {
      a[t] = *(const bf16x8*)&As[(wm * 64 + t * 16 + q) * 32 + g * 8];
      bb[t] = *(const bf16x8*)&Bs[(wn * 64 + t * 16 + q) * 32 + g * 8];
    }
#pragma unroll
    for (int mi = 0; mi < 4; ++mi)
#pragma unroll
      for (int ni = 0; ni < 4; ++ni)
        acc[mi][ni] = mfma_bf16(a[mi], bb[ni], acc[mi][ni]);
    __syncthreads();
  }
#pragma unroll
  for (int ni = 0; ni < 4; ++ni) {
    const int o = o0 + wn * 64 + ni * 16 + q;
    const float bias = out_b[o];
#pragma unroll
    for (int mi = 0; mi < 4; ++mi) {
      const int tokb = m0 + wm * 64 + mi * 16 + g * 4;
      const int b = tokb >> 12, n = tokb & (N_ - 1);
      const size_t idx = ((size_t)(b * C_ + o) << 12) + n;
      const float4 xv = *(const float4*)(x + idx);
      f32x4 t = acc[mi][ni];
      float4 r = make_float4(t[0] + bias + xv.x, t[1] + bias + xv.y,
                             t[2] + bias + xv.z, t[3] + bias + xv.w);
      *(float4*)(out + idx) = r;
    }
  }
}

extern "C" void kernel_launch(void* const* d_in, const int* in_sizes, int n_in,
                              void* d_out, int out_size, void* d_ws, size_t ws_size,
                              hipStream_t stream) {
  (void)in_sizes; (void)n_in; (void)out_size; (void)ws_size;
  const float* x = (const float*)d_in[0];
  const float* gn_w = (const float*)d_in[1];
  const float* gn_b = (const float*)d_in[2];
  const float* qkv_w = (const float*)d_in[3];
  const float* qkv_b = (const float*)d_in[4];
  const float* out_w = (const float*)d_in[5];
  const float* out_b = (const float*)d_in[6];
  float* out = (float*)d_out;

  char* ws = (char*)d_ws;
  float* gnscale = (float*)ws;              // 1024 f32
  float* gnshift = gnscale + 1024;          // 1024 f32
  bf16_t* w1bf = (bf16_t*)(ws + 8192);      // 196608 bf16
  bf16_t* w2bf = w1bf + 196608;             // 65536 bf16
  bf16_t* hbuf = w2bf + 65536;              // 4194304 bf16; Opart kh0 during attn
  bf16_t* Qb = hbuf + 4194304;              // Q; att buffer after combine
  bf16_t* Kb = Qb + 4194304;
  bf16_t* Vb = Kb + 4194304;
  bf16_t* op1 = Vb + 4194304;               // 4194304 bf16 (Opart kh1)
  float* lsum = (float*)(op1 + 4194304);    // 131072 f32

  k_pre<<<1152, 256, 0, stream>>>(x, gn_w, gn_b, qkv_w, out_w, gnscale, gnshift, w1bf, w2bf);
  k_gn_apply<<<512, 256, 0, stream>>>(x, gnscale, gnshift, hbuf);
  k_gemm_qkv<<<dim3(128, 6), 256, 0, stream>>>(hbuf, w1bf, qkv_b, Qb, Kb, Vb);
  k_attn<<<512, 512, 0, stream>>>(Qb, Kb, Vb, hbuf, op1, lsum);
  k_attn_combine<<<2048, 256, 0, stream>>>(hbuf, op1, lsum, Qb);
  k_gemm_out<<<dim3(128, 2), 256, 0, stream>>>(Qb, w2bf, out_b, x, out);
}

// Round 16
// 120.259 us; speedup vs baseline: 2.5493x; 1.0122x over previous
//
#include <hip/hip_runtime.h>
#include <cstdint>

typedef __bf16 bf16_t;
typedef __bf16 bf16x4 __attribute__((ext_vector_type(4)));
typedef __bf16 bf16x8 __attribute__((ext_vector_type(8)));
typedef float f32x4 __attribute__((ext_vector_type(4)));
typedef unsigned int u32x2 __attribute__((ext_vector_type(2)));
typedef unsigned int u32x4 __attribute__((ext_vector_type(4)));

#define B_ 4
#define C_ 256
#define N_ 4096
#define NH_ 4
#define HD_ 64

static __device__ __forceinline__ f32x4 mfma_bf16(bf16x8 a, bf16x8 b, f32x4 c) {
  return __builtin_amdgcn_mfma_f32_16x16x32_bf16(a, b, c, 0, 0, 0);
}

static __device__ __forceinline__ void async16(const void* g, void* l) {
  __builtin_amdgcn_global_load_lds(
      (__attribute__((address_space(1))) void*)(uintptr_t)g,
      (__attribute__((address_space(3))) void*)(uint32_t)(uintptr_t)l,
      16, 0, 0);
}

static __device__ __forceinline__ float fexp2(float x) {
#if __has_builtin(__builtin_amdgcn_exp2f)
  return __builtin_amdgcn_exp2f(x);  // raw v_exp_f32
#else
  return exp2f(x);
#endif
}

static __device__ __forceinline__ unsigned pack_bf16(float lo, float hi) {
  bf16x4 t;
  t[0] = (bf16_t)lo;
  t[1] = (bf16_t)hi;
  return *(unsigned*)&t;
}

// ---------------- kernel 1: GN stats (blocks 0-127) + weight cast (blocks 128+) ----------------
__global__ __launch_bounds__(256) void k_pre(const float* __restrict__ x,
                                             const float* __restrict__ gn_w,
                                             const float* __restrict__ gn_b,
                                             const float* __restrict__ qkv_w,
                                             const float* __restrict__ out_w,
                                             float* __restrict__ gnscale,
                                             float* __restrict__ gnshift,
                                             bf16_t* __restrict__ w1,
                                             bf16_t* __restrict__ w2) {
  __shared__ float red_s[4], red_ss[4];
  if (blockIdx.x >= 128) {
    int i = (blockIdx.x - 128) * 256 + threadIdx.x;
    if (i < 3 * C_ * C_) w1[i] = (bf16_t)qkv_w[i];
    else w2[i - 3 * C_ * C_] = (bf16_t)out_w[i - 3 * C_ * C_];
    return;
  }
  const int bg = blockIdx.x;
  const int b = bg >> 5, g = bg & 31;
  const float4* p4 = (const float4*)(x + (size_t)(b * C_ + g * 8) * N_);
  float s = 0.f, ss = 0.f;
  for (int i = threadIdx.x; i < 8192; i += 256) {
    float4 v = p4[i];
    s += (v.x + v.y) + (v.z + v.w);
    ss += (v.x * v.x + v.y * v.y) + (v.z * v.z + v.w * v.w);
  }
  for (int off = 32; off > 0; off >>= 1) {
    s += __shfl_down(s, off);
    ss += __shfl_down(ss, off);
  }
  const int wid = threadIdx.x >> 6, lane = threadIdx.x & 63;
  if (lane == 0) { red_s[wid] = s; red_ss[wid] = ss; }
  __syncthreads();
  if (threadIdx.x < 8) {
    float S = (red_s[0] + red_s[1]) + (red_s[2] + red_s[3]);
    float SS = (red_ss[0] + red_ss[1]) + (red_ss[2] + red_ss[3]);
    float mean = S * (1.f / 32768.f);
    float var = SS * (1.f / 32768.f) - mean * mean;
    float rstd = rsqrtf(var + 1e-5f);
    int c = g * 8 + threadIdx.x;
    float w = gn_w[c];
    gnscale[b * C_ + c] = w * rstd;
    gnshift[b * C_ + c] = gn_b[c] - mean * rstd * w;
  }
}

// ---------------- kernel 2: GN apply + transpose (LDS-coalesced) ----------------
__global__ __launch_bounds__(256) void k_gn_apply(const float* __restrict__ x,
                                                  const float* __restrict__ gnscale,
                                                  const float* __restrict__ gnshift,
                                                  bf16_t* __restrict__ h) {
  __shared__ bf16_t T[32 * 258];
  const int t = threadIdx.x;
  const int tok0 = blockIdx.x * 32;
  const int b = tok0 >> 12;
  const int n0 = tok0 & (N_ - 1);
  const int nl = t & 31, cset = t >> 5;
  const float* xb = x + ((size_t)(b * C_ + cset * 32) << 12) + n0 + nl;
  const float* scp = gnscale + b * C_ + cset * 32;
  const float* shp = gnshift + b * C_ + cset * 32;
#pragma unroll
  for (int j = 0; j < 32; ++j) {
    float y = xb[(size_t)j << 12] * scp[j] + shp[j];
    T[nl * 258 + cset * 32 + j] = (bf16_t)y;
  }
  __syncthreads();
  const int c4 = t & 63;
#pragma unroll
  for (int p = 0; p < 8; ++p) {
    const int tokl = p * 4 + (t >> 6);
    const int idx = tokl * 258 + c4 * 4;
    uint2 v;
    v.x = *(const unsigned*)&T[idx];
    v.y = *(const unsigned*)&T[idx + 2];
    *(uint2*)(h + ((size_t)(tok0 + tokl) << 8) + c4 * 4) = v;
  }
}

// ---------------- kernel 3: QKV GEMM ----------------
__global__ __launch_bounds__(256) void k_gemm_qkv(const bf16_t* __restrict__ h,
                                                  const bf16_t* __restrict__ w1,
                                                  const float* __restrict__ qkv_b,
                                                  bf16_t* __restrict__ Qb,
                                                  bf16_t* __restrict__ Kb,
                                                  bf16_t* __restrict__ Vb) {
  __shared__ bf16_t As[128 * 32], Bs[128 * 32];
  const int tid = threadIdx.x, lane = tid & 63, wid = tid >> 6;
  const int g = lane >> 4, q = lane & 15;
  const int wm = wid >> 1, wn = wid & 1;
  const int m0 = blockIdx.x * 128;
  const int o0 = blockIdx.y * 128;
  f32x4 acc[4][4] = {};
  const int srow = lane >> 2, scol = (lane & 3) * 8;
  for (int kc = 0; kc < 8; ++kc) {
    const int k0 = kc * 32;
#pragma unroll
    for (int j = 0; j < 2; ++j) {
      const int chunk = wid + j * 4;
      async16(h + (size_t)(m0 + chunk * 16 + srow) * C_ + k0 + scol, &As[chunk * 512]);
      async16(w1 + (size_t)(o0 + chunk * 16 + srow) * C_ + k0 + scol, &Bs[chunk * 512]);
    }
    __syncthreads();
    bf16x8 a[4], bb[4];
#pragma unroll
    for (int t = 0; t < 4; ++t) {
      a[t] = *(const bf16x8*)&As[(wm * 64 + t * 16 + q) * 32 + g * 8];
      bb[t] = *(const bf16x8*)&Bs[(wn * 64 + t * 16 + q) * 32 + g * 8];
    }
#pragma unroll
    for (int mi = 0; mi < 4; ++mi)
#pragma unroll
      for (int ni = 0; ni < 4; ++ni)
        acc[mi][ni] = mfma_bf16(a[mi], bb[ni], acc[mi][ni]);
    __syncthreads();
  }
  const float QSCALE = 0.1803368801111244f;  // (1/sqrt(64)) * log2(e)
#pragma unroll
  for (int ni = 0; ni < 4; ++ni) {
    const int o = o0 + wn * 64 + ni * 16 + q;
    const float bias = qkv_b[o];
    const int mat = o >> 8;
    const int c = o & 255, hh = c >> 6, d = c & 63;
#pragma unroll
    for (int mi = 0; mi < 4; ++mi) {
      const int tokb = m0 + wm * 64 + mi * 16 + g * 4;
      const int b = tokb >> 12, n = tokb & (N_ - 1);
      const size_t bh = (size_t)(b * NH_ + hh);
      f32x4 t = acc[mi][ni] + bias;
      if (mat == 0) {
#pragma unroll
        for (int r = 0; r < 4; ++r)
          Qb[(bh * N_ + n + r) * HD_ + d] = (bf16_t)(t[r] * QSCALE);
      } else if (mat == 1) {
#pragma unroll
        for (int r = 0; r < 4; ++r)
          Kb[(bh * N_ + n + r) * HD_ + d] = (bf16_t)t[r];
      } else {
        *(bf16x4*)(Vb + (bh * HD_ + d) * N_ + n) = __builtin_convertvector(t, bf16x4);
      }
    }
  }
}

// ---------------- kernel 4: flash attention — R5 best config (split-2, setprio) ----------------
__global__ __launch_bounds__(512) void k_attn(const bf16_t* __restrict__ Qb,
                                              const bf16_t* __restrict__ Kb,
                                              const bf16_t* __restrict__ Vb,
                                              bf16_t* __restrict__ op0,
                                              bf16_t* __restrict__ op1,
                                              float* __restrict__ lsum) {
  __shared__ __align__(16) bf16_t Ks[2][4096];  // [buf][key(64)][d(64)]
  __shared__ __align__(16) bf16_t Vs[2][4096];  // [buf][d(64)][key(64)]
  const int tid = threadIdx.x, lane = tid & 63, wid = tid >> 6;  // wid 0..7
  const int g = lane >> 4, q = lane & 15;
  const int qs = q & 7;
  int bid = blockIdx.x;
  bid = (bid & 7) * 64 + (bid >> 3);  // XCD-contiguous (512 % 8 == 0)
  const int kh = bid & 1;
  const int qt = (bid >> 1) & 15;
  const int bh = bid >> 5;
  const int nq0 = qt * 256 + wid * 32;
  const int k00 = kh * (N_ / 2);
  const int NT = (N_ / 2) / 64;  // 32
  const size_t base = (size_t)bh << 18;
  const bf16_t* Qp = Qb + base;
  const bf16_t* Kp = Kb + base;
  const bf16_t* Vp = Vb + base;

  const bf16x8 bqA0 = *(const bf16x8*)(Qp + (size_t)(nq0 + q) * HD_ + g * 8);
  const bf16x8 bqA1 = *(const bf16x8*)(Qp + (size_t)(nq0 + q) * HD_ + 32 + g * 8);
  const bf16x8 bqB0 = *(const bf16x8*)(Qp + (size_t)(nq0 + 16 + q) * HD_ + g * 8);
  const bf16x8 bqB1 = *(const bf16x8*)(Qp + (size_t)(nq0 + 16 + q) * HD_ + 32 + g * 8);

  const int srow = lane >> 3;
  const int sc16 = (lane & 7) ^ srow;

  f32x4 laccA = {}, laccB = {};
  f32x4 accA[4] = {}, accB[4] = {};
  bf16x8 ones;
#pragma unroll
  for (int i = 0; i < 8; ++i) ones[i] = (bf16_t)1.0f;

  async16(Kp + (size_t)(k00 + wid * 8 + srow) * HD_ + sc16 * 8, &Ks[0][wid * 512]);
  async16(Vp + (size_t)(wid * 8 + srow) * N_ + k00 + sc16 * 8, &Vs[0][wid * 512]);
  __syncthreads();

  const bf16_t* kS = Kp + (size_t)(k00 + 64 + wid * 8 + srow) * HD_ + sc16 * 8;
  const bf16_t* vS = Vp + (size_t)(wid * 8 + srow) * N_ + k00 + 64 + sc16 * 8;

  for (int t = 0; t < NT; ++t) {
    const int buf = t & 1;
    if (t < NT - 1) {
      async16(kS, &Ks[buf ^ 1][wid * 512]);
      async16(vS, &Vs[buf ^ 1][wid * 512]);
      kS += 64 * HD_;
      vS += 64;
    }
    const bf16_t* Kl = Ks[buf];
    const bf16_t* Vl = Vs[buf];
    f32x4 z = {0.f, 0.f, 0.f, 0.f};
    f32x4 sA[4], sB[4];
    __builtin_amdgcn_s_setprio(1);
#pragma unroll
    for (int kb = 0; kb < 4; ++kb) {
      bf16x8 k0 = *(const bf16x8*)(Kl + (kb * 16 + q) * 64 + ((g ^ qs) * 8));
      bf16x8 k1 = *(const bf16x8*)(Kl + (kb * 16 + q) * 64 + (((4 + g) ^ qs) * 8));
      sA[kb] = mfma_bf16(k0, bqA0, z);
      sB[kb] = mfma_bf16(k0, bqB0, z);
      sA[kb] = mfma_bf16(k1, bqA1, sA[kb]);
      sB[kb] = mfma_bf16(k1, bqB1, sB[kb]);
    }
    __builtin_amdgcn_s_setprio(0);
#pragma unroll
    for (int kb = 0; kb < 4; ++kb)
#pragma unroll
      for (int r = 0; r < 4; ++r) {
        sA[kb][r] = fexp2(sA[kb][r]);
        sB[kb][r] = fexp2(sB[kb][r]);
      }
    bf16x8 pbA[2], pbB[2];
#pragma unroll
    for (int s = 0; s < 2; ++s) {
      const f32x4* st = s ? sB : sA;
      bf16x8* pb = s ? pbB : pbA;
#pragma unroll
      for (int h = 0; h < 2; ++h) {
        unsigned u0 = pack_bf16(st[2 * h][0], st[2 * h][1]);
        unsigned u1 = pack_bf16(st[2 * h][2], st[2 * h][3]);
        unsigned u2 = pack_bf16(st[2 * h + 1][0], st[2 * h + 1][1]);
        unsigned u3 = pack_bf16(st[2 * h + 1][2], st[2 * h + 1][3]);
        u32x4 w;
#if __has_builtin(__builtin_amdgcn_permlane32_swap) && __has_builtin(__builtin_amdgcn_permlane16_swap)
        u32x2 a02 = __builtin_amdgcn_permlane32_swap(u0, u2, false, false);
        u32x2 r02 = __builtin_amdgcn_permlane16_swap(a02[0], a02[1], false, false);
        u32x2 a13 = __builtin_amdgcn_permlane32_swap(u1, u3, false, false);
        u32x2 r13 = __builtin_amdgcn_permlane16_swap(a13[0], a13[1], false, false);
        w[0] = r02[0]; w[2] = r02[1]; w[1] = r13[0]; w[3] = r13[1];
#else
        const int sl0 = (g & 1) * 32 + q, sl1 = sl0 + 16;
        w[0] = (g < 2) ? __shfl((int)u0, sl0) : __shfl((int)u2, sl0);
        w[1] = (g < 2) ? __shfl((int)u1, sl0) : __shfl((int)u3, sl0);
        w[2] = (g < 2) ? __shfl((int)u0, sl1) : __shfl((int)u2, sl1);
        w[3] = (g < 2) ? __shfl((int)u1, sl1) : __shfl((int)u3, sl1);
#endif
        pb[h] = *(bf16x8*)&w;
      }
    }
    __builtin_amdgcn_s_setprio(1);
    laccA = mfma_bf16(ones, pbA[0], laccA);
    laccA = mfma_bf16(ones, pbA[1], laccA);
    laccB = mfma_bf16(ones, pbB[0], laccB);
    laccB = mfma_bf16(ones, pbB[1], laccB);
#pragma unroll
    for (int db = 0; db < 4; ++db) {
      bf16x8 v0 = *(const bf16x8*)(Vl + (db * 16 + q) * 64 + ((g ^ qs) * 8));
      bf16x8 v1 = *(const bf16x8*)(Vl + (db * 16 + q) * 64 + (((4 + g) ^ qs) * 8));
      accA[db] = mfma_bf16(v0, pbA[0], accA[db]);
      accB[db] = mfma_bf16(v0, pbB[0], accB[db]);
      accA[db] = mfma_bf16(v1, pbA[1], accA[db]);
      accB[db] = mfma_bf16(v1, pbB[1], accB[db]);
    }
    __builtin_amdgcn_s_setprio(0);
    __syncthreads();
  }

  bf16_t* Op = (kh == 0 ? op0 : op1) + (size_t)bh * N_ * HD_;
  bf16_t* opA = Op + (size_t)(nq0 + q) * HD_;
  bf16_t* opB = opA + 16 * HD_;
#pragma unroll
  for (int db = 0; db < 4; ++db) {
    *(bf16x4*)(opA + db * 16 + g * 4) = __builtin_convertvector(accA[db], bf16x4);
    *(bf16x4*)(opB + db * 16 + g * 4) = __builtin_convertvector(accB[db], bf16x4);
  }
  if (g == 0) {
    const size_t mlb = (size_t)(kh * 16 + bh) * N_;
    lsum[mlb + nq0 + q] = laccA[0];
    lsum[mlb + nq0 + 16 + q] = laccB[0];
  }
}

// ---------------- kernel 5: out-proj GEMM with fused combine + bias + residual ----------------
// A-operand staged from the two attention partials: r = (o0+o1)*invl, packed
// and ds_write'd into the SAME As layout async16 produced. invl[4][128] (head,
// token) precomputed once per block in LDS.
__global__ __launch_bounds__(256) void k_gemm_out(const bf16_t* __restrict__ op0,
                                                  const bf16_t* __restrict__ op1,
                                                  const float* __restrict__ lsum,
                                                  const bf16_t* __restrict__ w2,
                                                  const float* __restrict__ out_b,
                                                  const float* __restrict__ x,
                                                  float* __restrict__ out) {
  __shared__ bf16_t As[128 * 32], Bs[128 * 32];
  __shared__ float invl[4 * 128];
  const int tid = threadIdx.x, lane = tid & 63, wid = tid >> 6;
  const int g = lane >> 4, q = lane & 15;
  const int wm = wid >> 1, wn = wid & 1;
  const int m0 = blockIdx.x * 128;
  const int o0c = blockIdx.y * 128;
  const int srow = lane >> 2, scol = (lane & 3) * 8;

  // precompute invl for this block's 128 tokens x 4 heads
#pragma unroll
  for (int ii = 0; ii < 2; ++ii) {
    const int idx = tid + ii * 256;
    const int hh = idx >> 7, tokl = idx & 127;
    const int tok = m0 + tokl;
    const int b = tok >> 12, n = tok & (N_ - 1);
    const int bh = b * NH_ + hh;
    const float l = lsum[(size_t)bh * N_ + n] + lsum[(size_t)(16 + bh) * N_ + n];
    invl[idx] = 1.0f / l;
  }
  __syncthreads();

  // this thread's staging coordinates (constant across kc)
  const int tokl_s = (wid & 3) * 16 + srow;        // covered via chunk loop below
  (void)tokl_s;

  f32x4 acc[4][4] = {};
  for (int kc = 0; kc < 8; ++kc) {
    const int k0 = kc * 32;
    const int hh = k0 >> 6;            // head for this 32-channel chunk (k0 32-aligned)
    const int d = (k0 & 63) + scol;    // channel-in-head for this thread
#pragma unroll
    for (int j = 0; j < 2; ++j) {
      const int chunk = wid + j * 4;
      // A: fused combine from partials
      const int tokl = chunk * 16 + srow;
      const int tok = m0 + tokl;
      const int b = tok >> 12, n = tok & (N_ - 1);
      const size_t ro = ((size_t)(b * NH_ + hh) * N_ + n) * HD_ + d;
      const bf16x8 a0 = *(const bf16x8*)(op0 + ro);
      const bf16x8 a1 = *(const bf16x8*)(op1 + ro);
      const float il = invl[hh * 128 + tokl];
      u32x4 wpk;
#pragma unroll
      for (int p = 0; p < 4; ++p)
        wpk[p] = pack_bf16(((float)a0[2 * p] + (float)a1[2 * p]) * il,
                           ((float)a0[2 * p + 1] + (float)a1[2 * p + 1]) * il);
      *(u32x4*)&As[chunk * 512 + srow * 32 + scol] = wpk;
      // B: weights via async16 (unchanged)
      async16(w2 + (size_t)(o0c + chunk * 16 + srow) * C_ + k0 + scol, &Bs[chunk * 512]);
    }
    __syncthreads();
    bf16x8 a[4], bb[4];
#pragma unroll
    for (int t = 0; t < 4; ++t) {
      a[t] = *(const bf16x8*)&As[(wm * 64 + t * 16 + q) * 32 + g * 8];
      bb[t] = *(const bf16x8*)&Bs[(wn * 64 + t * 16 + q) * 32 + g * 8];
    }
#pragma unroll
    for (int mi = 0; mi < 4; ++mi)
#pragma unroll
      for (int ni = 0; ni < 4; ++ni)
        acc[mi][ni] = mfma_bf16(a[mi], bb[ni], acc[mi][ni]);
    __syncthreads();
  }
#pragma unroll
  for (int ni = 0; ni < 4; ++ni) {
    const int o = o0c + wn * 64 + ni * 16 + q;
    const float bias = out_b[o];
#pragma unroll
    for (int mi = 0; mi < 4; ++mi) {
      const int tokb = m0 + wm * 64 + mi * 16 + g * 4;
      const int b = tokb >> 12, n = tokb & (N_ - 1);
      const size_t idx = ((size_t)(b * C_ + o) << 12) + n;
      const float4 xv = *(const float4*)(x + idx);
      f32x4 t = acc[mi][ni];
      float4 r = make_float4(t[0] + bias + xv.x, t[1] + bias + xv.y,
                             t[2] + bias + xv.z, t[3] + bias + xv.w);
      *(float4*)(out + idx) = r;
    }
  }
}

extern "C" void kernel_launch(void* const* d_in, const int* in_sizes, int n_in,
                              void* d_out, int out_size, void* d_ws, size_t ws_size,
                              hipStream_t stream) {
  (void)in_sizes; (void)n_in; (void)out_size; (void)ws_size;
  const float* x = (const float*)d_in[0];
  const float* gn_w = (const float*)d_in[1];
  const float* gn_b = (const float*)d_in[2];
  const float* qkv_w = (const float*)d_in[3];
  const float* qkv_b = (const float*)d_in[4];
  const float* out_w = (const float*)d_in[5];
  const float* out_b = (const float*)d_in[6];
  float* out = (float*)d_out;

  char* ws = (char*)d_ws;
  float* gnscale = (float*)ws;              // 1024 f32
  float* gnshift = gnscale + 1024;          // 1024 f32
  bf16_t* w1bf = (bf16_t*)(ws + 8192);      // 196608 bf16
  bf16_t* w2bf = w1bf + 196608;             // 65536 bf16
  bf16_t* hbuf = w2bf + 65536;              // 4194304 bf16; attn partial kh0
  bf16_t* Qb = hbuf + 4194304;
  bf16_t* Kb = Qb + 4194304;
  bf16_t* Vb = Kb + 4194304;
  bf16_t* op1 = Vb + 4194304;               // 4194304 bf16 (attn partial kh1)
  float* lsum = (float*)(op1 + 4194304);    // 131072 f32

  k_pre<<<1152, 256, 0, stream>>>(x, gn_w, gn_b, qkv_w, out_w, gnscale, gnshift, w1bf, w2bf);
  k_gn_apply<<<512, 256, 0, stream>>>(x, gnscale, gnshift, hbuf);
  k_gemm_qkv<<<dim3(128, 6), 256, 0, stream>>>(hbuf, w1bf, qkv_b, Qb, Kb, Vb);
  k_attn<<<512, 512, 0, stream>>>(Qb, Kb, Vb, hbuf, op1, lsum);
  k_gemm_out<<<dim3(128, 2), 256, 0, stream>>>(hbuf, op1, lsum, w2bf, out_b, x, out);
}

// Round 17
// 119.945 us; speedup vs baseline: 2.5559x; 1.0026x over previous
//
#include <hip/hip_runtime.h>
#include <cstdint>

typedef __bf16 bf16_t;
typedef __bf16 bf16x4 __attribute__((ext_vector_type(4)));
typedef __bf16 bf16x8 __attribute__((ext_vector_type(8)));
typedef float f32x4 __attribute__((ext_vector_type(4)));
typedef unsigned int u32x2 __attribute__((ext_vector_type(2)));
typedef unsigned int u32x4 __attribute__((ext_vector_type(4)));

#define B_ 4
#define C_ 256
#define N_ 4096
#define NH_ 4
#define HD_ 64

static __device__ __forceinline__ f32x4 mfma_bf16(bf16x8 a, bf16x8 b, f32x4 c) {
  return __builtin_amdgcn_mfma_f32_16x16x32_bf16(a, b, c, 0, 0, 0);
}

static __device__ __forceinline__ void async16(const void* g, void* l) {
  __builtin_amdgcn_global_load_lds(
      (__attribute__((address_space(1))) void*)(uintptr_t)g,
      (__attribute__((address_space(3))) void*)(uint32_t)(uintptr_t)l,
      16, 0, 0);
}

static __device__ __forceinline__ float fexp2(float x) {
#if __has_builtin(__builtin_amdgcn_exp2f)
  return __builtin_amdgcn_exp2f(x);  // raw v_exp_f32
#else
  return exp2f(x);
#endif
}

static __device__ __forceinline__ unsigned pack_bf16(float lo, float hi) {
  bf16x4 t;
  t[0] = (bf16_t)lo;
  t[1] = (bf16_t)hi;
  return *(unsigned*)&t;
}

// ---------------- kernel 1: GN stats (blocks 0-127) + weight cast (blocks 128+) ----------------
__global__ __launch_bounds__(256) void k_pre(const float* __restrict__ x,
                                             const float* __restrict__ gn_w,
                                             const float* __restrict__ gn_b,
                                             const float* __restrict__ qkv_w,
                                             const float* __restrict__ out_w,
                                             float* __restrict__ gnscale,
                                             float* __restrict__ gnshift,
                                             bf16_t* __restrict__ w1,
                                             bf16_t* __restrict__ w2) {
  __shared__ float red_s[4], red_ss[4];
  if (blockIdx.x >= 128) {
    int i = (blockIdx.x - 128) * 256 + threadIdx.x;
    if (i < 3 * C_ * C_) w1[i] = (bf16_t)qkv_w[i];
    else w2[i - 3 * C_ * C_] = (bf16_t)out_w[i - 3 * C_ * C_];
    return;
  }
  const int bg = blockIdx.x;
  const int b = bg >> 5, g = bg & 31;
  const float4* p4 = (const float4*)(x + (size_t)(b * C_ + g * 8) * N_);
  float s = 0.f, ss = 0.f;
  for (int i = threadIdx.x; i < 8192; i += 256) {
    float4 v = p4[i];
    s += (v.x + v.y) + (v.z + v.w);
    ss += (v.x * v.x + v.y * v.y) + (v.z * v.z + v.w * v.w);
  }
  for (int off = 32; off > 0; off >>= 1) {
    s += __shfl_down(s, off);
    ss += __shfl_down(ss, off);
  }
  const int wid = threadIdx.x >> 6, lane = threadIdx.x & 63;
  if (lane == 0) { red_s[wid] = s; red_ss[wid] = ss; }
  __syncthreads();
  if (threadIdx.x < 8) {
    float S = (red_s[0] + red_s[1]) + (red_s[2] + red_s[3]);
    float SS = (red_ss[0] + red_ss[1]) + (red_ss[2] + red_ss[3]);
    float mean = S * (1.f / 32768.f);
    float var = SS * (1.f / 32768.f) - mean * mean;
    float rstd = rsqrtf(var + 1e-5f);
    int c = g * 8 + threadIdx.x;
    float w = gn_w[c];
    gnscale[b * C_ + c] = w * rstd;
    gnshift[b * C_ + c] = gn_b[c] - mean * rstd * w;
  }
}

// ---------------- kernel 2: GN apply + transpose (LDS-coalesced) ----------------
__global__ __launch_bounds__(256) void k_gn_apply(const float* __restrict__ x,
                                                  const float* __restrict__ gnscale,
                                                  const float* __restrict__ gnshift,
                                                  bf16_t* __restrict__ h) {
  __shared__ bf16_t T[32 * 258];
  const int t = threadIdx.x;
  const int tok0 = blockIdx.x * 32;
  const int b = tok0 >> 12;
  const int n0 = tok0 & (N_ - 1);
  const int nl = t & 31, cset = t >> 5;
  const float* xb = x + ((size_t)(b * C_ + cset * 32) << 12) + n0 + nl;
  const float* scp = gnscale + b * C_ + cset * 32;
  const float* shp = gnshift + b * C_ + cset * 32;
#pragma unroll
  for (int j = 0; j < 32; ++j) {
    float y = xb[(size_t)j << 12] * scp[j] + shp[j];
    T[nl * 258 + cset * 32 + j] = (bf16_t)y;
  }
  __syncthreads();
  const int c4 = t & 63;
#pragma unroll
  for (int p = 0; p < 8; ++p) {
    const int tokl = p * 4 + (t >> 6);
    const int idx = tokl * 258 + c4 * 4;
    uint2 v;
    v.x = *(const unsigned*)&T[idx];
    v.y = *(const unsigned*)&T[idx + 2];
    *(uint2*)(h + ((size_t)(tok0 + tokl) << 8) + c4 * 4) = v;
  }
}

// ---------------- kernel 3: QKV GEMM ----------------
__global__ __launch_bounds__(256) void k_gemm_qkv(const bf16_t* __restrict__ h,
                                                  const bf16_t* __restrict__ w1,
                                                  const float* __restrict__ qkv_b,
                                                  bf16_t* __restrict__ Qb,
                                                  bf16_t* __restrict__ Kb,
                                                  bf16_t* __restrict__ Vb) {
  __shared__ bf16_t As[128 * 32], Bs[128 * 32];
  const int tid = threadIdx.x, lane = tid & 63, wid = tid >> 6;
  const int g = lane >> 4, q = lane & 15;
  const int wm = wid >> 1, wn = wid & 1;
  const int m0 = blockIdx.x * 128;
  const int o0 = blockIdx.y * 128;
  f32x4 acc[4][4] = {};
  const int srow = lane >> 2, scol = (lane & 3) * 8;
  for (int kc = 0; kc < 8; ++kc) {
    const int k0 = kc * 32;
#pragma unroll
    for (int j = 0; j < 2; ++j) {
      const int chunk = wid + j * 4;
      async16(h + (size_t)(m0 + chunk * 16 + srow) * C_ + k0 + scol, &As[chunk * 512]);
      async16(w1 + (size_t)(o0 + chunk * 16 + srow) * C_ + k0 + scol, &Bs[chunk * 512]);
    }
    __syncthreads();
    bf16x8 a[4], bb[4];
#pragma unroll
    for (int t = 0; t < 4; ++t) {
      a[t] = *(const bf16x8*)&As[(wm * 64 + t * 16 + q) * 32 + g * 8];
      bb[t] = *(const bf16x8*)&Bs[(wn * 64 + t * 16 + q) * 32 + g * 8];
    }
#pragma unroll
    for (int mi = 0; mi < 4; ++mi)
#pragma unroll
      for (int ni = 0; ni < 4; ++ni)
        acc[mi][ni] = mfma_bf16(a[mi], bb[ni], acc[mi][ni]);
    __syncthreads();
  }
  const float QSCALE = 0.1803368801111244f;  // (1/sqrt(64)) * log2(e)
#pragma unroll
  for (int ni = 0; ni < 4; ++ni) {
    const int o = o0 + wn * 64 + ni * 16 + q;
    const float bias = qkv_b[o];
    const int mat = o >> 8;
    const int c = o & 255, hh = c >> 6, d = c & 63;
#pragma unroll
    for (int mi = 0; mi < 4; ++mi) {
      const int tokb = m0 + wm * 64 + mi * 16 + g * 4;
      const int b = tokb >> 12, n = tokb & (N_ - 1);
      const size_t bh = (size_t)(b * NH_ + hh);
      f32x4 t = acc[mi][ni] + bias;
      if (mat == 0) {
#pragma unroll
        for (int r = 0; r < 4; ++r)
          Qb[(bh * N_ + n + r) * HD_ + d] = (bf16_t)(t[r] * QSCALE);
      } else if (mat == 1) {
#pragma unroll
        for (int r = 0; r < 4; ++r)
          Kb[(bh * N_ + n + r) * HD_ + d] = (bf16_t)t[r];
      } else {
        *(bf16x4*)(Vb + (bh * HD_ + d) * N_ + n) = __builtin_convertvector(t, bf16x4);
      }
    }
  }
}

// ---------------- kernel 4: flash attention — 2 tiles per barrier (quad-buffer) ----------------
// R15 body unchanged; K/V quad-buffered (64 KB, still 2 blocks/CU) and the
// barrier runs once per 128-key PAIR instead of per 64-key tile (32 -> 16
// barriers/wave). Pair p stages the half last read at pair p-1 (safe: all
// waves passed p-1's barrier); compute reads data drained at p-1's barrier.
__global__ __launch_bounds__(512) void k_attn(const bf16_t* __restrict__ Qb,
                                              const bf16_t* __restrict__ Kb,
                                              const bf16_t* __restrict__ Vb,
                                              bf16_t* __restrict__ op0,
                                              bf16_t* __restrict__ op1,
                                              float* __restrict__ lsum) {
  __shared__ __align__(16) bf16_t Ks[4][4096];  // [slot][key(64)][d(64)]
  __shared__ __align__(16) bf16_t Vs[4][4096];  // [slot][d(64)][key(64)]
  const int tid = threadIdx.x, lane = tid & 63, wid = tid >> 6;  // wid 0..7
  const int g = lane >> 4, q = lane & 15;
  const int qs = q & 7;
  int bid = blockIdx.x;
  bid = (bid & 7) * 64 + (bid >> 3);  // XCD-contiguous (512 % 8 == 0)
  const int kh = bid & 1;
  const int qt = (bid >> 1) & 15;
  const int bh = bid >> 5;
  const int nq0 = qt * 256 + wid * 32;
  const int k00 = kh * (N_ / 2);
  const int NP = (N_ / 2) / 128;  // 16 pairs
  const size_t base = (size_t)bh << 18;
  const bf16_t* Qp = Qb + base;
  const bf16_t* Kp = Kb + base;
  const bf16_t* Vp = Vb + base;

  const bf16x8 bqA0 = *(const bf16x8*)(Qp + (size_t)(nq0 + q) * HD_ + g * 8);
  const bf16x8 bqA1 = *(const bf16x8*)(Qp + (size_t)(nq0 + q) * HD_ + 32 + g * 8);
  const bf16x8 bqB0 = *(const bf16x8*)(Qp + (size_t)(nq0 + 16 + q) * HD_ + g * 8);
  const bf16x8 bqB1 = *(const bf16x8*)(Qp + (size_t)(nq0 + 16 + q) * HD_ + 32 + g * 8);

  const int srow = lane >> 3;
  const int sc16 = (lane & 7) ^ srow;

  f32x4 laccA = {}, laccB = {};
  f32x4 accA[4] = {}, accB[4] = {};
  bf16x8 ones;
#pragma unroll
  for (int i = 0; i < 8; ++i) ones[i] = (bf16_t)1.0f;

  // prologue: stage tiles 0,1 into slots 0,1
  async16(Kp + (size_t)(k00 + wid * 8 + srow) * HD_ + sc16 * 8, &Ks[0][wid * 512]);
  async16(Vp + (size_t)(wid * 8 + srow) * N_ + k00 + sc16 * 8, &Vs[0][wid * 512]);
  async16(Kp + (size_t)(k00 + 64 + wid * 8 + srow) * HD_ + sc16 * 8, &Ks[1][wid * 512]);
  async16(Vp + (size_t)(wid * 8 + srow) * N_ + k00 + 64 + sc16 * 8, &Vs[1][wid * 512]);
  __syncthreads();

  const bf16_t* kS = Kp + (size_t)(k00 + 128 + wid * 8 + srow) * HD_ + sc16 * 8;
  const bf16_t* vS = Vp + (size_t)(wid * 8 + srow) * N_ + k00 + 128 + sc16 * 8;

  for (int p = 0; p < NP; ++p) {
    const int cs = (p & 1) * 2;  // compute slots cs, cs+1
    if (p < NP - 1) {
      const int ssl = ((p + 1) & 1) * 2;  // stage slots
      async16(kS, &Ks[ssl][wid * 512]);
      async16(vS, &Vs[ssl][wid * 512]);
      async16(kS + 64 * HD_, &Ks[ssl + 1][wid * 512]);
      async16(vS + 64, &Vs[ssl + 1][wid * 512]);
      kS += 128 * HD_;
      vS += 128;
    }
#pragma unroll
    for (int u = 0; u < 2; ++u) {
      const bf16_t* Kl = Ks[cs + u];
      const bf16_t* Vl = Vs[cs + u];
      f32x4 z = {0.f, 0.f, 0.f, 0.f};
      f32x4 sA[4], sB[4];
      __builtin_amdgcn_s_setprio(1);
#pragma unroll
      for (int kb = 0; kb < 4; ++kb) {
        bf16x8 k0 = *(const bf16x8*)(Kl + (kb * 16 + q) * 64 + ((g ^ qs) * 8));
        bf16x8 k1 = *(const bf16x8*)(Kl + (kb * 16 + q) * 64 + (((4 + g) ^ qs) * 8));
        sA[kb] = mfma_bf16(k0, bqA0, z);
        sB[kb] = mfma_bf16(k0, bqB0, z);
        sA[kb] = mfma_bf16(k1, bqA1, sA[kb]);
        sB[kb] = mfma_bf16(k1, bqB1, sB[kb]);
      }
      __builtin_amdgcn_s_setprio(0);
#pragma unroll
      for (int kb = 0; kb < 4; ++kb)
#pragma unroll
        for (int r = 0; r < 4; ++r) {
          sA[kb][r] = fexp2(sA[kb][r]);
          sB[kb][r] = fexp2(sB[kb][r]);
        }
      bf16x8 pbA[2], pbB[2];
#pragma unroll
      for (int s = 0; s < 2; ++s) {
        const f32x4* st = s ? sB : sA;
        bf16x8* pb = s ? pbB : pbA;
#pragma unroll
        for (int h = 0; h < 2; ++h) {
          unsigned u0 = pack_bf16(st[2 * h][0], st[2 * h][1]);
          unsigned u1 = pack_bf16(st[2 * h][2], st[2 * h][3]);
          unsigned u2 = pack_bf16(st[2 * h + 1][0], st[2 * h + 1][1]);
          unsigned u3 = pack_bf16(st[2 * h + 1][2], st[2 * h + 1][3]);
          u32x4 w;
#if __has_builtin(__builtin_amdgcn_permlane32_swap) && __has_builtin(__builtin_amdgcn_permlane16_swap)
          u32x2 a02 = __builtin_amdgcn_permlane32_swap(u0, u2, false, false);
          u32x2 r02 = __builtin_amdgcn_permlane16_swap(a02[0], a02[1], false, false);
          u32x2 a13 = __builtin_amdgcn_permlane32_swap(u1, u3, false, false);
          u32x2 r13 = __builtin_amdgcn_permlane16_swap(a13[0], a13[1], false, false);
          w[0] = r02[0]; w[2] = r02[1]; w[1] = r13[0]; w[3] = r13[1];
#else
          const int sl0 = (g & 1) * 32 + q, sl1 = sl0 + 16;
          w[0] = (g < 2) ? __shfl((int)u0, sl0) : __shfl((int)u2, sl0);
          w[1] = (g < 2) ? __shfl((int)u1, sl0) : __shfl((int)u3, sl0);
          w[2] = (g < 2) ? __shfl((int)u0, sl1) : __shfl((int)u2, sl1);
          w[3] = (g < 2) ? __shfl((int)u1, sl1) : __shfl((int)u3, sl1);
#endif
          pb[h] = *(bf16x8*)&w;
        }
      }
      __builtin_amdgcn_s_setprio(1);
      laccA = mfma_bf16(ones, pbA[0], laccA);
      laccA = mfma_bf16(ones, pbA[1], laccA);
      laccB = mfma_bf16(ones, pbB[0], laccB);
      laccB = mfma_bf16(ones, pbB[1], laccB);
#pragma unroll
      for (int db = 0; db < 4; ++db) {
        bf16x8 v0 = *(const bf16x8*)(Vl + (db * 16 + q) * 64 + ((g ^ qs) * 8));
        bf16x8 v1 = *(const bf16x8*)(Vl + (db * 16 + q) * 64 + (((4 + g) ^ qs) * 8));
        accA[db] = mfma_bf16(v0, pbA[0], accA[db]);
        accB[db] = mfma_bf16(v0, pbB[0], accB[db]);
        accA[db] = mfma_bf16(v1, pbA[1], accA[db]);
        accB[db] = mfma_bf16(v1, pbB[1], accB[db]);
      }
      __builtin_amdgcn_s_setprio(0);
    }
    __syncthreads();
  }

  bf16_t* Op = (kh == 0 ? op0 : op1) + (size_t)bh * N_ * HD_;
  bf16_t* opA = Op + (size_t)(nq0 + q) * HD_;
  bf16_t* opB = opA + 16 * HD_;
#pragma unroll
  for (int db = 0; db < 4; ++db) {
    *(bf16x4*)(opA + db * 16 + g * 4) = __builtin_convertvector(accA[db], bf16x4);
    *(bf16x4*)(opB + db * 16 + g * 4) = __builtin_convertvector(accB[db], bf16x4);
  }
  if (g == 0) {
    const size_t mlb = (size_t)(kh * 16 + bh) * N_;
    lsum[mlb + nq0 + q] = laccA[0];
    lsum[mlb + nq0 + 16 + q] = laccB[0];
  }
}

// ---------------- kernel 5: out-proj GEMM with fused combine + bias + residual ----------------
__global__ __launch_bounds__(256) void k_gemm_out(const bf16_t* __restrict__ op0,
                                                  const bf16_t* __restrict__ op1,
                                                  const float* __restrict__ lsum,
                                                  const bf16_t* __restrict__ w2,
                                                  const float* __restrict__ out_b,
                                                  const float* __restrict__ x,
                                                  float* __restrict__ out) {
  __shared__ bf16_t As[128 * 32], Bs[128 * 32];
  __shared__ float invl[4 * 128];
  const int tid = threadIdx.x, lane = tid & 63, wid = tid >> 6;
  const int g = lane >> 4, q = lane & 15;
  const int wm = wid >> 1, wn = wid & 1;
  const int m0 = blockIdx.x * 128;
  const int o0c = blockIdx.y * 128;
  const int srow = lane >> 2, scol = (lane & 3) * 8;

#pragma unroll
  for (int ii = 0; ii < 2; ++ii) {
    const int idx = tid + ii * 256;
    const int hh = idx >> 7, tokl = idx & 127;
    const int tok = m0 + tokl;
    const int b = tok >> 12, n = tok & (N_ - 1);
    const int bh = b * NH_ + hh;
    const float l = lsum[(size_t)bh * N_ + n] + lsum[(size_t)(16 + bh) * N_ + n];
    invl[idx] = 1.0f / l;
  }
  __syncthreads();

  f32x4 acc[4][4] = {};
  for (int kc = 0; kc < 8; ++kc) {
    const int k0 = kc * 32;
    const int hh = k0 >> 6;
    const int d = (k0 & 63) + scol;
#pragma unroll
    for (int j = 0; j < 2; ++j) {
      const int chunk = wid + j * 4;
      const int tokl = chunk * 16 + srow;
      const int tok = m0 + tokl;
      const int b = tok >> 12, n = tok & (N_ - 1);
      const size_t ro = ((size_t)(b * NH_ + hh) * N_ + n) * HD_ + d;
      const bf16x8 a0 = *(const bf16x8*)(op0 + ro);
      const bf16x8 a1 = *(const bf16x8*)(op1 + ro);
      const float il = invl[hh * 128 + tokl];
      u32x4 wpk;
#pragma unroll
      for (int p = 0; p < 4; ++p)
        wpk[p] = pack_bf16(((float)a0[2 * p] + (float)a1[2 * p]) * il,
                           ((float)a0[2 * p + 1] + (float)a1[2 * p + 1]) * il);
      *(u32x4*)&As[chunk * 512 + srow * 32 + scol] = wpk;
      async16(w2 + (size_t)(o0c + chunk * 16 + srow) * C_ + k0 + scol, &Bs[chunk * 512]);
    }
    __syncthreads();
    bf16x8 a[4], bb[4];
#pragma unroll
    for (int t = 0; t < 4; ++t) {
      a[t] = *(const bf16x8*)&As[(wm * 64 + t * 16 + q) * 32 + g * 8];
      bb[t] = *(const bf16x8*)&Bs[(wn * 64 + t * 16 + q) * 32 + g * 8];
    }
#pragma unroll
    for (int mi = 0; mi < 4; ++mi)
#pragma unroll
      for (int ni = 0; ni < 4; ++ni)
        acc[mi][ni] = mfma_bf16(a[mi], bb[ni], acc[mi][ni]);
    __syncthreads();
  }
#pragma unroll
  for (int ni = 0; ni < 4; ++ni) {
    const int o = o0c + wn * 64 + ni * 16 + q;
    const float bias = out_b[o];
#pragma unroll
    for (int mi = 0; mi < 4; ++mi) {
      const int tokb = m0 + wm * 64 + mi * 16 + g * 4;
      const int b = tokb >> 12, n = tokb & (N_ - 1);
      const size_t idx = ((size_t)(b * C_ + o) << 12) + n;
      const float4 xv = *(const float4*)(x + idx);
      f32x4 t = acc[mi][ni];
      float4 r = make_float4(t[0] + bias + xv.x, t[1] + bias + xv.y,
                             t[2] + bias + xv.z, t[3] + bias + xv.w);
      *(float4*)(out + idx) = r;
    }
  }
}

extern "C" void kernel_launch(void* const* d_in, const int* in_sizes, int n_in,
                              void* d_out, int out_size, void* d_ws, size_t ws_size,
                              hipStream_t stream) {
  (void)in_sizes; (void)n_in; (void)out_size; (void)ws_size;
  const float* x = (const float*)d_in[0];
  const float* gn_w = (const float*)d_in[1];
  const float* gn_b = (const float*)d_in[2];
  const float* qkv_w = (const float*)d_in[3];
  const float* qkv_b = (const float*)d_in[4];
  const float* out_w = (const float*)d_in[5];
  const float* out_b = (const float*)d_in[6];
  float* out = (float*)d_out;

  char* ws = (char*)d_ws;
  float* gnscale = (float*)ws;              // 1024 f32
  float* gnshift = gnscale + 1024;          // 1024 f32
  bf16_t* w1bf = (bf16_t*)(ws + 8192);      // 196608 bf16
  bf16_t* w2bf = w1bf + 196608;             // 65536 bf16
  bf16_t* hbuf = w2bf + 65536;              // 4194304 bf16; attn partial kh0
  bf16_t* Qb = hbuf + 4194304;
  bf16_t* Kb = Qb + 4194304;
  bf16_t* Vb = Kb + 4194304;
  bf16_t* op1 = Vb + 4194304;               // 4194304 bf16 (attn partial kh1)
  float* lsum = (float*)(op1 + 4194304);    // 131072 f32

  k_pre<<<1152, 256, 0, stream>>>(x, gn_w, gn_b, qkv_w, out_w, gnscale, gnshift, w1bf, w2bf);
  k_gn_apply<<<512, 256, 0, stream>>>(x, gnscale, gnshift, hbuf);
  k_gemm_qkv<<<dim3(128, 6), 256, 0, stream>>>(hbuf, w1bf, qkv_b, Qb, Kb, Vb);
  k_attn<<<512, 512, 0, stream>>>(Qb, Kb, Vb, hbuf, op1, lsum);
  k_gemm_out<<<dim3(128, 2), 256, 0, stream>>>(hbuf, op1, lsum, w2bf, out_b, x, out);
}